// Round 6
// baseline (250.763 us; speedup 1.0000x reference)
//
#include <hip/hip_runtime.h>

// Problem constants (match reference): B=16, T=4096, E=768.
constexpr int Bc = 16;
constexpr int Tc = 4096;
constexpr int Ec = 768;
constexpr int PSTRIDE = Ec + 4;   // per-partial: [l, pad, pad, pad, o[768]] (16B-aligned o)

// tanh(x) = 1 - 2/(e^2x + 1). No clamp needed: e=+inf -> 1, e=0 -> -1 (correct limits).
__device__ __forceinline__ float fast_tanh(float x) {
    float e = __expf(2.0f * x);
    return fmaf(-2.0f, __builtin_amdgcn_rcpf(e + 1.0f), 1.0f);
}

__device__ __forceinline__ float dot_tanh4(float4 c, float4 w) {
    float s = fast_tanh(c.x) * w.x;
    s = fmaf(fast_tanh(c.y), w.y, s);
    s = fmaf(fast_tanh(c.z), w.z, s);
    s = fmaf(fast_tanh(c.w), w.w, s);
    return s;
}

__device__ __forceinline__ float4 ld4(const float* p) {
    return *reinterpret_cast<const float4*>(p);
}

// Non-temporal 16B load: no L3 allocate -> no dirty-line eviction stall on the
// read path; context has zero reuse so L3 buys nothing. (round-5 verified win)
using vf4 = __attribute__((ext_vector_type(4))) float;
__device__ __forceinline__ float4 ldnt4(const float* p) {
    vf4 v = __builtin_nontemporal_load(reinterpret_cast<const vf4*>(p));
    return make_float4(v.x, v.y, v.z, v.w);
}

// Kernel 1: per (b, chunk) block, UNSHIFTED softmax accumulation.
// |score| <= sum|v_w[E:]| ~ 15.7 so e^s is always in fp32 range (no max-shift);
// shift-invariance drops the tanh(query).v_w[:E] term (exact). Masked rows are
// skipped exactly (exp(-1e10-m)==0 in fp32). All 4 waves see the same 64-row
// ballot; wave w takes set-bits of rank w, w+4, w+8, ... -> per-block work
// balance is +-1 row (vs binomial straggler tail with contiguous strips).
// Rows processed in PAIRS with a one-pair-ahead software pipeline (12 NT
// float4 loads in flight per wave).
template<int C>
__global__ __launch_bounds__(256, 4) void attn_partial(
    const float* __restrict__ ctx, const int* __restrict__ mask,
    const float* __restrict__ v_w, float* __restrict__ parts)
{
    constexpr int RPB = Tc / C;        // rows per block (multiple of 64)
    const int b    = blockIdx.x / C;
    const int c    = blockIdx.x % C;
    const int wave = threadIdx.x >> 6;
    const int lane = threadIdx.x & 63;

    const float4 vw0 = ld4(v_w + Ec + 0 * 256 + 4 * lane);
    const float4 vw1 = ld4(v_w + Ec + 1 * 256 + 4 * lane);
    const float4 vw2 = ld4(v_w + Ec + 2 * 256 + 4 * lane);

    float  l  = 0.0f;
    float4 o0 = make_float4(0.f, 0.f, 0.f, 0.f), o1 = o0, o2 = o0;

    const int    brow0 = c * RPB;
    const float* cb    = ctx + (long)b * Tc * Ec;

    for (int g = 0; g < RPB; g += 64) {
        const int mv = mask[b * Tc + brow0 + g + lane];        // 64 block rows
        unsigned long long mb = __ballot(mv != 0);             // same in all 4 waves
        const int cnt = __popcll(mb);
        // wave w handles bit-ranks w, w+4, w+8, ...
        mb &= mb - (wave >= 1);   // drop lowest bit if wave>=1 (x & (x-1); x&x-0=x)
        mb &= mb - (wave >= 2);
        mb &= mb - (wave >= 3);
        const int mycnt = (cnt > wave) ? ((cnt - wave + 3) >> 2) : 0;
        if (!mycnt) continue;

        auto pop = [&]() -> const float* {
            int r = (int)__ffsll((long long)mb) - 1;
            mb &= mb - 1; mb &= mb - 1; mb &= mb - 1; mb &= mb - 1;  // skip 4 ranks
            return cb + (long)(brow0 + g + r) * Ec + 4 * lane;
        };

        float4 a0, a1, a2, a3, a4, a5;
        auto compute_pair = [&]() {
            float s0 = dot_tanh4(a0, vw0) + dot_tanh4(a1, vw1) + dot_tanh4(a2, vw2);
            float s1 = dot_tanh4(a3, vw0) + dot_tanh4(a4, vw1) + dot_tanh4(a5, vw2);
#pragma unroll
            for (int off = 32; off > 0; off >>= 1) {           // two chains interleave
                s0 += __shfl_xor(s0, off, 64);
                s1 += __shfl_xor(s1, off, 64);
            }
            const float p0 = __expf(s0), p1 = __expf(s1);
            l += p0 + p1;
            o0.x = fmaf(p0, a0.x, fmaf(p1, a3.x, o0.x));
            o0.y = fmaf(p0, a0.y, fmaf(p1, a3.y, o0.y));
            o0.z = fmaf(p0, a0.z, fmaf(p1, a3.z, o0.z));
            o0.w = fmaf(p0, a0.w, fmaf(p1, a3.w, o0.w));
            o1.x = fmaf(p0, a1.x, fmaf(p1, a4.x, o1.x));
            o1.y = fmaf(p0, a1.y, fmaf(p1, a4.y, o1.y));
            o1.z = fmaf(p0, a1.z, fmaf(p1, a4.z, o1.z));
            o1.w = fmaf(p0, a1.w, fmaf(p1, a4.w, o1.w));
            o2.x = fmaf(p0, a2.x, fmaf(p1, a5.x, o2.x));
            o2.y = fmaf(p0, a2.y, fmaf(p1, a5.y, o2.y));
            o2.z = fmaf(p0, a2.z, fmaf(p1, a5.z, o2.z));
            o2.w = fmaf(p0, a2.w, fmaf(p1, a5.w, o2.w));
        };

        const int pairs = mycnt >> 1;
        if (pairs) {
            { const float* p = pop(); a0 = ldnt4(p); a1 = ldnt4(p + 256); a2 = ldnt4(p + 512);
              const float* q = pop(); a3 = ldnt4(q); a4 = ldnt4(q + 256); a5 = ldnt4(q + 512); }
            for (int pi = 1; pi < pairs; ++pi) {
                const float* p = pop();
                float4 n0 = ldnt4(p), n1 = ldnt4(p + 256), n2 = ldnt4(p + 512);
                const float* q = pop();
                float4 n3 = ldnt4(q), n4 = ldnt4(q + 256), n5 = ldnt4(q + 512);
                compute_pair();
                a0 = n0; a1 = n1; a2 = n2; a3 = n3; a4 = n4; a5 = n5;
            }
            compute_pair();
        }
        if (mycnt & 1) {                                        // odd tail row
            const float* p = pop();
            a0 = ldnt4(p); a1 = ldnt4(p + 256); a2 = ldnt4(p + 512);
            float s = dot_tanh4(a0, vw0) + dot_tanh4(a1, vw1) + dot_tanh4(a2, vw2);
#pragma unroll
            for (int off = 32; off > 0; off >>= 1)
                s += __shfl_xor(s, off, 64);
            const float pw = __expf(s);
            l += pw;
            o0.x = fmaf(pw, a0.x, o0.x); o0.y = fmaf(pw, a0.y, o0.y);
            o0.z = fmaf(pw, a0.z, o0.z); o0.w = fmaf(pw, a0.w, o0.w);
            o1.x = fmaf(pw, a1.x, o1.x); o1.y = fmaf(pw, a1.y, o1.y);
            o1.z = fmaf(pw, a1.z, o1.z); o1.w = fmaf(pw, a1.w, o1.w);
            o2.x = fmaf(pw, a2.x, o2.x); o2.y = fmaf(pw, a2.y, o2.y);
            o2.z = fmaf(pw, a2.z, o2.z); o2.w = fmaf(pw, a2.w, o2.w);
        }
    }

    // Combine the block's 4 wave partials in LDS (plain sums), write one partial.
    __shared__ float sl[4];
    __shared__ float so[4][Ec];
    if (lane == 0) sl[wave] = l;
    *reinterpret_cast<float4*>(&so[wave][0 * 256 + 4 * lane]) = o0;
    *reinterpret_cast<float4*>(&so[wave][1 * 256 + 4 * lane]) = o1;
    *reinterpret_cast<float4*>(&so[wave][2 * 256 + 4 * lane]) = o2;
    __syncthreads();

    float* part = parts + ((long)b * C + c) * PSTRIDE;
    if (threadIdx.x == 0) part[0] = sl[0] + sl[1] + sl[2] + sl[3];
    if (threadIdx.x < 192) {
        const int e = 4 * threadIdx.x;
        float4 s0 = *reinterpret_cast<float4*>(&so[0][e]);
        float4 s1 = *reinterpret_cast<float4*>(&so[1][e]);
        float4 s2 = *reinterpret_cast<float4*>(&so[2][e]);
        float4 s3 = *reinterpret_cast<float4*>(&so[3][e]);
        float4 rs = make_float4(s0.x + s1.x + s2.x + s3.x,
                                s0.y + s1.y + s2.y + s3.y,
                                s0.z + s1.z + s2.z + s3.z,
                                s0.w + s1.w + s2.w + s3.w);
        *reinterpret_cast<float4*>(part + 4 + e) = rs;
    }
}

// Kernel 2: plain-sum combine of C partials per batch row + one divide.
// grid = (B, 3); each block handles 256 output features. Fully unrolled.
template<int C>
__global__ __launch_bounds__(256) void attn_reduce(
    const float* __restrict__ parts, float* __restrict__ out)
{
    const int b   = blockIdx.x;
    const int tid = threadIdx.x;
    const float* pb = parts + (long)b * C * PSTRIDE;

    float lsum = 0.0f;
#pragma unroll
    for (int k = 0; k < C; ++k) lsum += pb[k * PSTRIDE];

    const int e = blockIdx.y * 256 + tid;
    float acc = 0.0f;
#pragma unroll
    for (int k = 0; k < C; ++k) acc += pb[k * PSTRIDE + 4 + e];

    out[b * Ec + e] = acc / lsum;
}

template<int C>
static void run_pipeline(const float* ctx, const int* mask, const float* vw,
                         float* ws, float* out, hipStream_t stream)
{
    attn_partial<C><<<dim3(Bc * C), 256, 0, stream>>>(ctx, mask, vw, ws);
    attn_reduce<C><<<dim3(Bc, 3), 256, 0, stream>>>(ws, out);
}

extern "C" void kernel_launch(void* const* d_in, const int* in_sizes, int n_in,
                              void* d_out, int out_size, void* d_ws, size_t ws_size,
                              hipStream_t stream)
{
    (void)in_sizes; (void)n_in; (void)out_size;
    // setup_inputs order: query[0] (unused — softmax shift-invariant),
    // context[1], mask[2], v_w[3].
    const float* ctx  = (const float*)d_in[1];
    const int*   mask = (const int*)d_in[2];
    const float* vw   = (const float*)d_in[3];
    float* out = (float*)d_out;
    float* ws  = (float*)d_ws;

    const size_t need64 = (size_t)Bc * 64 * PSTRIDE * sizeof(float);
    const size_t need16 = (size_t)Bc * 16 * PSTRIDE * sizeof(float);
    const size_t need4  = (size_t)Bc * 4  * PSTRIDE * sizeof(float);

    if (ws_size >= need64)      run_pipeline<64>(ctx, mask, vw, ws, out, stream);
    else if (ws_size >= need16) run_pipeline<16>(ctx, mask, vw, ws, out, stream);
    else if (ws_size >= need4)  run_pipeline<4>(ctx, mask, vw, ws, out, stream);
    else                        run_pipeline<1>(ctx, mask, vw, ws, out, stream);
}